// Round 2
// 220.627 us; speedup vs baseline: 1.0482x; 1.0482x over previous
//
#include <hip/hip_runtime.h>
#include <cstddef>
#include <cstdint>

#define T_SEQ 100

typedef __attribute__((ext_vector_type(8))) short bfrag;
typedef __attribute__((ext_vector_type(4))) float f4;

union FragU { uint32_t u[4]; bfrag v; };

__device__ __forceinline__ float fast_tanh(float x) {
    float e = __expf(2.0f * x);
    float r = __builtin_amdgcn_rcpf(e + 1.0f);
    return 1.0f - 2.0f * r;
}

__device__ __forceinline__ float exp2_fast(float x) {
#if __has_builtin(__builtin_amdgcn_exp2f)
    return __builtin_amdgcn_exp2f(x);
#else
    return __expf(x * 0.6931471805599453f);
#endif
}

// tanh(o)*scale = scale - 2*scale / (2^(o*2*log2e) + 1)
__device__ __forceinline__ float tanh_mul(float o, float scale, float s2) {
    float rr = __builtin_amdgcn_rcpf(exp2_fast(o * 2.8853900817779268f) + 1.0f);
    return fmaf(-s2, rr, scale);
}

// f32 pair -> packed bf16 (RNE), one instruction per pair.
// Register-only inline asm: no memory side effects, no waitcnt hazards.
// (gfx950 has v_cvt_pk_bf16_f32 but no builtin for it — learn_hip m240.)
#if __has_builtin(__builtin_amdgcn_cvt_pk_bf16_f32)
typedef __attribute__((ext_vector_type(2))) __bf16 bf16x2;
__device__ __forceinline__ uint32_t cvtpk(float lo, float hi) {
    bf16x2 p = __builtin_amdgcn_cvt_pk_bf16_f32(lo, hi);
    return __builtin_bit_cast(uint32_t, p);
}
#else
__device__ __forceinline__ uint32_t cvtpk(float lo, float hi) {
    uint32_t r;
    asm("v_cvt_pk_bf16_f32 %0, %1, %2" : "=v"(r) : "v"(lo), "v"(hi));
    return r;
}
#endif

__device__ __forceinline__ void pack8(const float a[8], bfrag& out) {
    FragU O;
    #pragma unroll
    for (int q = 0; q < 4; ++q)
        O.u[q] = cvtpk(a[2 * q], a[2 * q + 1]);
    out = O.v;
}

__device__ __forceinline__ f4 mfma_(bfrag a, bfrag b, f4 c) {
    return __builtin_amdgcn_mfma_f32_16x16x32_bf16(a, b, c, 0, 0, 0);
}

// ============================================================================
// Serial recurrence: one wave = 16 elements, Euler step (1 feval/t).
// Depth-5 rotating prefetch with statically-named slots and PLAIN HIP loads:
// the compiler sees the full dataflow and emits exact counted s_waitcnt
// itself (no inline-asm memory ops — those are unsound under regalloc).
// Each slot's load is issued 5 bodies (~1500 cy) before its consume, covering
// the ~900 cy HBM miss latency. pack8 is one v_cvt_pk_bf16_f32 per f32 pair.
// z(t) stored packed-bf16 to zws; mu computed by the parallel mu_kernel.
// ============================================================================
__global__ __launch_bounds__(64, 1)
void latode_serial(const float* __restrict__ dt,  const float* __restrict__ x,
                   const float* __restrict__ We1, const float* __restrict__ be1,
                   const float* __restrict__ We2, const float* __restrict__ be2,
                   const float* __restrict__ Wf1, const float* __restrict__ bf1,
                   const float* __restrict__ Wf2, const float* __restrict__ bf2,
                   uint32_t* __restrict__ zws, int B)
{
    const int l = threadIdx.x;
    const int g = l >> 4;
    const int m = l & 15;
    const int e = blockIdx.x * 16 + m;
    const int js0 = 8 * (m >> 2) + (m & 3);
    const int js1 = js0 + 4;

    float tmp[8];
    bfrag A0, A1, X0, X1, W0, W1;   // single RNE-bf16 weight fragments

    #pragma unroll
    for (int jj = 0; jj < 8; ++jj) {
        int sig = 16 * (jj >> 2) + 4 * g + (jj & 3);
        tmp[jj] = (js0 < 20) ? Wf1[sig * 20 + js0] : 0.0f;
    }
    pack8(tmp, A0);
    #pragma unroll
    for (int jj = 0; jj < 8; ++jj) {
        int sig = 16 * (jj >> 2) + 4 * g + (jj & 3);
        tmp[jj] = (js1 < 20) ? Wf1[sig * 20 + js1] : 0.0f;
    }
    pack8(tmp, A1);
    #pragma unroll
    for (int jj = 0; jj < 8; ++jj) {
        int kx = 8 * g + jj;
        tmp[jj] = (js0 < 20) ? Wf1[(32 + kx) * 20 + js0] : 0.0f;
    }
    pack8(tmp, X0);
    #pragma unroll
    for (int jj = 0; jj < 8; ++jj) {
        int kx = 8 * g + jj;
        tmp[jj] = (js1 < 20) ? Wf1[(32 + kx) * 20 + js1] : 0.0f;
    }
    pack8(tmp, X1);
    #pragma unroll
    for (int jj = 0; jj < 8; ++jj) {
        int j = 8 * g + jj;
        tmp[jj] = (j < 20) ? Wf2[j * 32 + m] : 0.0f;
    }
    pack8(tmp, W0);
    #pragma unroll
    for (int jj = 0; jj < 8; ++jj) {
        int j = 8 * g + jj;
        tmp[jj] = (j < 20) ? Wf2[j * 32 + 16 + m] : 0.0f;
    }
    pack8(tmp, W1);

    f4 bias0, bias1, cb0, cb1;
    #pragma unroll
    for (int r = 0; r < 4; ++r) {
        bias0[r] = bf2[4 * g + r];
        bias1[r] = bf2[16 + 4 * g + r];
        int j0 = 8 * g + r;     cb0[r] = (j0 < 20) ? bf1[j0] : 0.0f;
        int j1 = 8 * g + r + 4; cb1[r] = (j1 < 20) ? bf1[j1] : 0.0f;
    }

    const float* xe  = x  + (size_t)e * T_SEQ * 32;
    const float* xp  = xe + 8 * g;
    const float* dte = dt + (size_t)e * T_SEQ * 2;
    uint32_t* zrow = zws + (size_t)e * T_SEQ * 16;

    // ---- depth-5 rotating slots (statically named — never runtime-indexed) ----
    struct XBuf { float4 a, b; float2 d; };
    XBuf S0, S1, S2, S3, S4;
    auto load_into = [&](XBuf& Bf, int t) {
        const float* xr = xp + (size_t)t * 32;
        Bf.a = *(const float4*)(xr);
        Bf.b = *(const float4*)(xr + 4);
        Bf.d = *(const float2*)(dte + 2 * t);
    };

    // Prologue: fill all 5 slots before the z0-encode; the encode's ~600
    // independent FMAs cover the initial load latency.
    load_into(S0, 0); load_into(S1, 1); load_into(S2, 2);
    load_into(S3, 3); load_into(S4, 4);

    // ---- z0 encode (scalar fp32, once) ----
    float z[8];
    {
        float x0v[32];
        #pragma unroll
        for (int i = 0; i < 32; i += 4) {
            float4 v = *(const float4*)(xe + i);
            x0v[i] = v.x; x0v[i+1] = v.y; x0v[i+2] = v.z; x0v[i+3] = v.w;
        }
        float h10[10];
        #pragma unroll
        for (int r = 0; r < 10; ++r) {
            float s = be1[r];
            #pragma unroll
            for (int i = 0; i < 32; ++i) s += x0v[i] * We1[i * 10 + r];
            h10[r] = fast_tanh(s);
        }
        #pragma unroll
        for (int jj = 0; jj < 8; ++jj) {
            int sig = 16 * (jj >> 2) + 4 * g + (jj & 3);
            float s = be2[sig];
            #pragma unroll
            for (int r = 0; r < 10; ++r) s += h10[r] * We2[r * 32 + sig];
            z[jj] = fast_tanh(s);
        }
    }

    f4 cx0, cx1;
    float scale;
    auto consume = [&](const XBuf& S, f4& o0, f4& o1, float& os) {
        float xt[8] = { S.a.x, S.a.y, S.a.z, S.a.w,
                        S.b.x, S.b.y, S.b.z, S.b.w };
        bfrag xf; pack8(xt, xf);
        o0 = mfma_(X0, xf, cb0);
        o1 = mfma_(X1, xf, cb1);
        os = (S.d.y - S.d.x) * 0.01f;
    };

    consume(S0, cx0, cx1, scale);   // cx for t=0
    load_into(S0, 5);               // refill S0 <- t=5

    // One sub-iteration: S holds data for time t+1; body(t) uses cx/scale
    // computed in the previous sub-iteration.
    auto subiter = [&](int t, XBuf& S) {
        f4 ncx0, ncx1; float nsc;
        consume(S, ncx0, ncx1, nsc);           // waits on load issued 5 bodies ago

        int tl = t + 6;                         // refill S <- t+6 (clamped)
        if (tl > T_SEQ - 1) tl = T_SEQ - 1;
        load_into(S, tl);

        // ---- Euler body for time t ----
        const float s2 = scale + scale;
        bfrag bb; pack8(z, bb);
        f4 p0 = mfma_(A0, bb, cx0);
        f4 p1 = mfma_(A1, bb, cx1);
        float pr[8];
        #pragma unroll
        for (int r = 0; r < 4; ++r) {
            pr[r]     = fmaxf(p0[r], 0.0f);
            pr[4 + r] = fmaxf(p1[r], 0.0f);
        }
        bfrag pf; pack8(pr, pf);
        f4 o0 = mfma_(W0, pf, bias0);
        f4 o1 = mfma_(W1, pf, bias1);
        #pragma unroll
        for (int r = 0; r < 4; ++r) {
            z[r]     += tanh_mul(o0[r], scale, s2);
            z[4 + r] += tanh_mul(o1[r], scale, s2);
        }
        bfrag zf; pack8(z, zf);
        FragU P; P.v = zf;
        uint32_t* rowp = zrow + (uint32_t)t * 16;
        *(uint2*)(rowp + 2 * g)     = make_uint2(P.u[0], P.u[1]);
        *(uint2*)(rowp + 8 + 2 * g) = make_uint2(P.u[2], P.u[3]);

        cx0 = ncx0; cx1 = ncx1; scale = nsc;
    };

    #pragma unroll 1
    for (int tb = 0; tb < T_SEQ; tb += 5) {
        subiter(tb + 0, S1);
        subiter(tb + 1, S2);
        subiter(tb + 2, S3);
        subiter(tb + 3, S4);
        subiter(tb + 4, S0);
    }
}

// Parallel mu head: one thread per (e,t) row.
__global__ __launch_bounds__(256, 4)
void mu_kernel(const uint32_t* __restrict__ zws,
               const float* __restrict__ Wm1, const float* __restrict__ bm1,
               const float* __restrict__ Wm2, const float* __restrict__ bm2,
               float* __restrict__ out, int nrows)
{
    int row = blockIdx.x * 256 + threadIdx.x;
    if (row >= nrows) return;
    const uint4* zp = (const uint4*)(zws + (size_t)row * 16);
    uint4 q0 = zp[0], q1 = zp[1], q2 = zp[2], q3 = zp[3];
    uint32_t du[16] = { q0.x, q0.y, q0.z, q0.w, q1.x, q1.y, q1.z, q1.w,
                        q2.x, q2.y, q2.z, q2.w, q3.x, q3.y, q3.z, q3.w };
    float zf[32];
    #pragma unroll
    for (int d = 0; d < 16; ++d) {
        uint32_t u = du[d];
        zf[2 * d]     = __uint_as_float(u << 16);
        zf[2 * d + 1] = __uint_as_float(u & 0xFFFF0000u);
    }
    float v[10];
    #pragma unroll
    for (int r = 0; r < 10; ++r) v[r] = bm1[r];
    #pragma unroll
    for (int i = 0; i < 32; ++i) {
        float zi = zf[i];
        #pragma unroll
        for (int r = 0; r < 10; ++r) v[r] = fmaf(zi, Wm1[i * 10 + r], v[r]);
    }
    float mu = bm2[0];
    #pragma unroll
    for (int r = 0; r < 10; ++r) mu += fast_tanh(v[r]) * Wm2[r];
    out[row] = mu;
}

// ============================================================================
// Fallback (ws too small / B not /16): fused Euler, mu in-loop.
// ============================================================================
__global__ __launch_bounds__(64, 1)
void latode_fused(const float* __restrict__ dt,  const float* __restrict__ x,
                  const float* __restrict__ We1, const float* __restrict__ be1,
                  const float* __restrict__ We2, const float* __restrict__ be2,
                  const float* __restrict__ Wf1, const float* __restrict__ bf1,
                  const float* __restrict__ Wf2, const float* __restrict__ bf2,
                  const float* __restrict__ Wm1, const float* __restrict__ bm1,
                  const float* __restrict__ Wm2, const float* __restrict__ bm2,
                  float* __restrict__ out, int B)
{
    const int l = threadIdx.x;
    const int g = l >> 4;
    const int m = l & 15;
    const int e = blockIdx.x * 16 + m;
    if (e >= B) return;
    const int js0 = 8 * (m >> 2) + (m & 3);
    const int js1 = js0 + 4;

    float tmp[8];
    bfrag A0, A1, X0, X1, W0, W1, M0;
    #pragma unroll
    for (int jj = 0; jj < 8; ++jj) {
        int sig = 16 * (jj >> 2) + 4 * g + (jj & 3);
        tmp[jj] = (js0 < 20) ? Wf1[sig * 20 + js0] : 0.0f;
    }
    pack8(tmp, A0);
    #pragma unroll
    for (int jj = 0; jj < 8; ++jj) {
        int sig = 16 * (jj >> 2) + 4 * g + (jj & 3);
        tmp[jj] = (js1 < 20) ? Wf1[sig * 20 + js1] : 0.0f;
    }
    pack8(tmp, A1);
    #pragma unroll
    for (int jj = 0; jj < 8; ++jj) {
        int kx = 8 * g + jj;
        tmp[jj] = (js0 < 20) ? Wf1[(32 + kx) * 20 + js0] : 0.0f;
    }
    pack8(tmp, X0);
    #pragma unroll
    for (int jj = 0; jj < 8; ++jj) {
        int kx = 8 * g + jj;
        tmp[jj] = (js1 < 20) ? Wf1[(32 + kx) * 20 + js1] : 0.0f;
    }
    pack8(tmp, X1);
    #pragma unroll
    for (int jj = 0; jj < 8; ++jj) {
        int j = 8 * g + jj;
        tmp[jj] = (j < 20) ? Wf2[j * 32 + m] : 0.0f;
    }
    pack8(tmp, W0);
    #pragma unroll
    for (int jj = 0; jj < 8; ++jj) {
        int j = 8 * g + jj;
        tmp[jj] = (j < 20) ? Wf2[j * 32 + 16 + m] : 0.0f;
    }
    pack8(tmp, W1);
    #pragma unroll
    for (int jj = 0; jj < 8; ++jj) {
        int sig = 16 * (jj >> 2) + 4 * g + (jj & 3);
        tmp[jj] = (m < 10) ? Wm1[sig * 10 + m] : 0.0f;
    }
    pack8(tmp, M0);

    f4 bias0, bias1, cb0, cb1, bmv;
    float wm2r[4];
    #pragma unroll
    for (int r = 0; r < 4; ++r) {
        bias0[r] = bf2[4 * g + r];
        bias1[r] = bf2[16 + 4 * g + r];
        int j0 = 8 * g + r;     cb0[r] = (j0 < 20) ? bf1[j0] : 0.0f;
        int j1 = 8 * g + r + 4; cb1[r] = (j1 < 20) ? bf1[j1] : 0.0f;
        int vr = 4 * g + r;
        bmv[r]  = (vr < 10) ? bm1[vr] : 0.0f;
        wm2r[r] = (vr < 10) ? Wm2[vr] : 0.0f;
    }

    const float* xe  = x  + (size_t)e * T_SEQ * 32;
    const float* dte = dt + (size_t)e * T_SEQ * 2;

    float z[8];
    {
        float x0v[32];
        #pragma unroll
        for (int i = 0; i < 32; i += 4) {
            float4 v = *(const float4*)(xe + i);
            x0v[i] = v.x; x0v[i+1] = v.y; x0v[i+2] = v.z; x0v[i+3] = v.w;
        }
        float h10[10];
        #pragma unroll
        for (int r = 0; r < 10; ++r) {
            float s = be1[r];
            #pragma unroll
            for (int i = 0; i < 32; ++i) s += x0v[i] * We1[i * 10 + r];
            h10[r] = fast_tanh(s);
        }
        #pragma unroll
        for (int jj = 0; jj < 8; ++jj) {
            int sig = 16 * (jj >> 2) + 4 * g + (jj & 3);
            float s = be2[sig];
            #pragma unroll
            for (int r = 0; r < 10; ++r) s += h10[r] * We2[r * 32 + sig];
            z[jj] = fast_tanh(s);
        }
    }

    const float bm2s = bm2[0];
    f4 cx0, cx1;
    float scale;
    {
        float4 va = *(const float4*)(xe + 8 * g);
        float4 vb = *(const float4*)(xe + 8 * g + 4);
        float2 dd = *(const float2*)(dte);
        float xt[8] = { va.x, va.y, va.z, va.w, vb.x, vb.y, vb.z, vb.w };
        bfrag xf; pack8(xt, xf);
        cx0 = mfma_(X0, xf, cb0);
        cx1 = mfma_(X1, xf, cb1);
        scale = (dd.y - dd.x) * 0.01f;
    }

    for (int t = 0; t < T_SEQ; ++t) {
        int tn = (t + 1 < T_SEQ) ? (t + 1) : t;
        const float* xr = xe + tn * 32 + 8 * g;
        float4 na = *(const float4*)(xr);
        float4 nb = *(const float4*)(xr + 4);
        float2 nd = *(const float2*)(dte + 2 * tn);
        const float s2 = scale + scale;

        bfrag bb; pack8(z, bb);
        f4 p0 = mfma_(A0, bb, cx0);
        f4 p1 = mfma_(A1, bb, cx1);
        float pr[8];
        #pragma unroll
        for (int r = 0; r < 4; ++r) {
            pr[r]     = fmaxf(p0[r], 0.0f);
            pr[4 + r] = fmaxf(p1[r], 0.0f);
        }
        bfrag pf; pack8(pr, pf);
        f4 o0 = mfma_(W0, pf, bias0);
        f4 o1 = mfma_(W1, pf, bias1);
        #pragma unroll
        for (int r = 0; r < 4; ++r) {
            z[r]     += tanh_mul(o0[r], scale, s2);
            z[4 + r] += tanh_mul(o1[r], scale, s2);
        }

        {
            float xt[8] = { na.x, na.y, na.z, na.w, nb.x, nb.y, nb.z, nb.w };
            bfrag xf; pack8(xt, xf);
            cx0 = mfma_(X0, xf, cb0);
            cx1 = mfma_(X1, xf, cb1);
            scale = (nd.y - nd.x) * 0.01f;
        }

        bfrag zf; pack8(z, zf);
        f4 vv = mfma_(M0, zf, bmv);
        float p = 0.0f;
        #pragma unroll
        for (int r = 0; r < 4; ++r) p += fast_tanh(vv[r]) * wm2r[r];
        p += __shfl_xor(p, 16, 64);
        p += __shfl_xor(p, 32, 64);
        if (l < 16) out[(size_t)e * T_SEQ + t] = p + bm2s;
    }
}

extern "C" void kernel_launch(void* const* d_in, const int* in_sizes, int n_in,
                              void* d_out, int out_size, void* d_ws, size_t ws_size,
                              hipStream_t stream) {
    const float* dt  = (const float*)d_in[0];
    const float* x   = (const float*)d_in[1];
    const float* We1 = (const float*)d_in[2];
    const float* be1 = (const float*)d_in[3];
    const float* We2 = (const float*)d_in[4];
    const float* be2 = (const float*)d_in[5];
    const float* Wf1 = (const float*)d_in[6];
    const float* bf1 = (const float*)d_in[7];
    const float* Wf2 = (const float*)d_in[8];
    const float* bf2 = (const float*)d_in[9];
    const float* Wm1 = (const float*)d_in[10];
    const float* bm1 = (const float*)d_in[11];
    const float* Wm2 = (const float*)d_in[12];
    const float* bm2 = (const float*)d_in[13];
    float* out = (float*)d_out;

    const int B = in_sizes[0] / (T_SEQ * 2);   // 8192
    const size_t zbytes = (size_t)B * T_SEQ * 32 * 2;

    if (ws_size >= zbytes && (B % 16) == 0) {
        hipLaunchKernelGGL(latode_serial, dim3(B / 16), dim3(64), 0, stream,
                           dt, x, We1, be1, We2, be2, Wf1, bf1, Wf2, bf2,
                           (uint32_t*)d_ws, B);
        int nrows = B * T_SEQ;
        hipLaunchKernelGGL(mu_kernel, dim3((nrows + 255) / 256), dim3(256), 0, stream,
                           (const uint32_t*)d_ws, Wm1, bm1, Wm2, bm2, out, nrows);
    } else {
        hipLaunchKernelGGL(latode_fused, dim3((B + 15) / 16), dim3(64), 0, stream,
                           dt, x, We1, be1, We2, be2, Wf1, bf1, Wf2, bf2,
                           Wm1, bm1, Wm2, bm2, out, B);
    }
}